// Round 12
// baseline (214.192 us; speedup 1.0000x reference)
//
#include <hip/hip_runtime.h>
#include <hip/hip_bf16.h>

typedef __attribute__((ext_vector_type(16))) float f32x16;
typedef __attribute__((ext_vector_type(8))) int i32x8;

#define T_TOK 1370
#define DDIM  768
#define SCV   1369   // valid tokens per slab
#define SCP   1408   // s slab padded rows (11*128)
#define MQP   1536   // q padded rows (6*256)
#define NB    8
#define NSLAB 32
#define NST   44     // s tiles of 128 (4 slabs * 11)
#define NMT   6      // m tiles of 256

#define MEMFENCE asm volatile("" ::: "memory")
#define BARRIER  do { __builtin_amdgcn_s_barrier(); MEMFENCE; } while (0)

#define GLOAD_LDS16(g, l)                                                     \
  __builtin_amdgcn_global_load_lds(                                           \
      (const __attribute__((address_space(1))) unsigned int*)(g),             \
      (__attribute__((address_space(3))) unsigned int*)(l), 16, 0, 0)

// One block per output row: mean over 3 layers -> l2norm -> fp8 e4m3 store.
// dst layout: [slabs][pad][768] fp8, rows >= 1369 zeroed. pad via gridDim.x.
extern "C" __global__ __launch_bounds__(192) void prep_kernel(
    const float* __restrict__ src, unsigned char* __restrict__ dst,
    size_t lstride)
{
  const int row  = blockIdx.x;
  const int slab = blockIdx.y;
  const int t    = threadIdx.x;  // 0..191, each owns one float4 (768 = 192*4)
  unsigned char* drow = dst + ((size_t)slab * gridDim.x + row) * DDIM;
  if (row >= SCV) {
    reinterpret_cast<unsigned int*>(drow)[t] = 0u;
    return;
  }
  const float* base = src + ((size_t)slab * T_TOK + row + 1) * DDIM;
  float4 a = reinterpret_cast<const float4*>(base)[t];
  float4 b = reinterpret_cast<const float4*>(base + lstride)[t];
  float4 c = reinterpret_cast<const float4*>(base + 2 * lstride)[t];
  const float k3 = 1.0f / 3.0f;
  float4 m;
  m.x = (a.x + b.x + c.x) * k3;
  m.y = (a.y + b.y + c.y) * k3;
  m.z = (a.z + b.z + c.z) * k3;
  m.w = (a.w + b.w + c.w) * k3;
  float ss = m.x * m.x + m.y * m.y + m.z * m.z + m.w * m.w;
  #pragma unroll
  for (int d = 1; d < 64; d <<= 1) ss += __shfl_xor(ss, d);
  __shared__ float wsum[3];
  if ((t & 63) == 0) wsum[t >> 6] = ss;
  __syncthreads();
  float tot = wsum[0] + wsum[1] + wsum[2];
  float rn = 1.0f / fmaxf(sqrtf(tot), 1e-12f);
  int pk = __builtin_amdgcn_cvt_pk_fp8_f32(m.x * rn, m.y * rn, 0, false);
  pk = __builtin_amdgcn_cvt_pk_fp8_f32(m.z * rn, m.w * rn, pk, true);
  reinterpret_cast<unsigned int*>(drow)[t] = (unsigned int)pk;
}

// 256x128 tile, BK=64, MX-fp8 32x32x64 MFMA (scale=1.0), 4 waves
// (2Mx2N, per-wave 128x64 = 4x2 frags of 32x32), ring-3 LDS (72 KB),
// counted vmcnt(6), 2 blocks/CU. part: [8][44][1536] float.
extern "C" __global__ __launch_bounds__(256, 2) void simmax_kernel(
    const unsigned char* __restrict__ xq,
    const unsigned char* __restrict__ xs,
    float* __restrict__ part)
{
  // XCD-chunked bijective remap: nwg = 2112 = 8*264; XCD k owns batch n=k,
  // mt varies fastest so 6 consecutive blocks share one B s-tile.
  const int flat = blockIdx.x + NMT * (blockIdx.y + NST * blockIdx.z);
  const int swz  = (flat & 7) * (NMT * NST) + (flat >> 3);
  const int mt   = swz % NMT;
  const int st   = (swz / NMT) % NST;
  const int n    = swz / (NMT * NST);

  const int tid  = threadIdx.x;
  const int lane = tid & 63;
  const int w    = tid >> 6;    // 0..3
  const int wr   = w >> 1;      // 0..1 (128-row band of 256)
  const int wc   = w & 1;       // 0..1 (64-col half of 128)
  const int l31  = lane & 31;
  const int h    = lane >> 5;

  // ring: [3] x (A 256x64B = 16 KB | B 128x64B = 8 KB) = 72 KB
  __shared__ unsigned char ring[3][24576];

  const int slab = st / 11;
  const int lt   = st - slab * 11;
  const unsigned char* gA = xq + ((size_t)n * MQP + (size_t)mt * 256) * DDIM;
  const unsigned char* gB =
      xs + ((size_t)(n * 4 + slab) * SCP + (size_t)lt * 128) * DDIM;

  // staging: 1-KB chunks = 16 rows x 64 B. A = 16 chunks (wave owns w*4..+3),
  // B = 8 chunks (wave owns w*2..+1). lane -> row c*16+(lane>>2), 16-B slot
  // lane&3. Source pre-swizzled slot^(row&3); LDS dest linear; reads XOR the
  // same involution => 2 lanes/bank uniform (free).
  int aoffg[4], aldso[4], boffg[2], bldso[2];
  #pragma unroll
  for (int i = 0; i < 4; ++i) {
    int c = w * 4 + i;
    int r = c * 16 + (lane >> 2);
    aoffg[i] = r * DDIM + (((lane & 3) ^ (r & 3)) << 4);
    aldso[i] = c * 1024;
  }
  #pragma unroll
  for (int i = 0; i < 2; ++i) {
    int c = w * 2 + i;
    int r = c * 16 + (lane >> 2);
    boffg[i] = r * DDIM + (((lane & 3) ^ (r & 3)) << 4);
    bldso[i] = 16384 + c * 1024;   // B region starts at 16 KB
  }

  // fragment read byte offsets: row*64 + (((2h)^(row&3))<<4); hi 16B at ^16.
  // A row = wr*128 + mf*32 + l31; B row = wc*64 + nf*32 + l31.
  int aoff[4], boff[2];
  #pragma unroll
  for (int mf = 0; mf < 4; ++mf) {
    int row = wr * 128 + mf * 32 + l31;
    aoff[mf] = row * 64 + ((((h << 1) ^ (row & 3))) << 4);
  }
  #pragma unroll
  for (int nf = 0; nf < 2; ++nf) {
    int row = wc * 64 + nf * 32 + l31;
    boff[nf] = 16384 + row * 64 + ((((h << 1) ^ (row & 3))) << 4);
  }

  f32x16 acc[4][2];
  {
    f32x16 zz = {0.f,0.f,0.f,0.f,0.f,0.f,0.f,0.f,
                 0.f,0.f,0.f,0.f,0.f,0.f,0.f,0.f};
    #pragma unroll
    for (int a = 0; a < 4; ++a)
      #pragma unroll
      for (int b = 0; b < 2; ++b) acc[a][b] = zz;
  }

  #define ISSUE(KT, RB)                                                      \
    do {                                                                     \
      const unsigned char* ga_ = gA + (KT) * 64;                             \
      const unsigned char* gb_ = gB + (KT) * 64;                             \
      unsigned char* lb_ = ring[RB];                                         \
      _Pragma("unroll") for (int i = 0; i < 4; ++i)                          \
        GLOAD_LDS16(ga_ + aoffg[i], lb_ + aldso[i]);                         \
      _Pragma("unroll") for (int i = 0; i < 2; ++i)                          \
        GLOAD_LDS16(gb_ + boffg[i], lb_ + bldso[i]);                         \
    } while (0)

  // prologue: fill pipeline 2 deep (6 loads/thread per step)
  ISSUE(0, 0);
  ISSUE(1, 1);
  asm volatile("s_waitcnt vmcnt(6)" ::: "memory");  // kt0 landed, kt1 flying
  BARRIER;

  for (int kt = 0; kt < 12; ++kt) {
    if (kt + 2 < 12) ISSUE(kt + 2, (kt + 2) % 3);

    const char* Cb = reinterpret_cast<const char*>(ring[kt % 3]);
    i32x8 bfr[2];
    #pragma unroll
    for (int nf = 0; nf < 2; ++nf) {
      int4 lo = *reinterpret_cast<const int4*>(Cb + boff[nf]);
      int4 hi = *reinterpret_cast<const int4*>(Cb + (boff[nf] ^ 16));
      bfr[nf] = i32x8{lo.x, lo.y, lo.z, lo.w, hi.x, hi.y, hi.z, hi.w};
    }
    __builtin_amdgcn_s_setprio(1);
    #pragma unroll
    for (int mf = 0; mf < 4; ++mf) {
      int4 lo = *reinterpret_cast<const int4*>(Cb + aoff[mf]);
      int4 hi = *reinterpret_cast<const int4*>(Cb + (aoff[mf] ^ 16));
      i32x8 af = i32x8{lo.x, lo.y, lo.z, lo.w, hi.x, hi.y, hi.z, hi.w};
      #pragma unroll
      for (int nf = 0; nf < 2; ++nf)
        acc[mf][nf] = __builtin_amdgcn_mfma_scale_f32_32x32x64_f8f6f4(
            af, bfr[nf], acc[mf][nf], 0, 0, 0, 127, 0, 127);
    }
    __builtin_amdgcn_s_setprio(0);

    // wait for NEXT buffer's batch (issued a full K-step ago); keep the
    // just-issued 6 in flight across the barrier.
    if (kt < 10)       asm volatile("s_waitcnt vmcnt(6)" ::: "memory");
    else if (kt == 10) asm volatile("s_waitcnt vmcnt(0)" ::: "memory");
    if (kt < 11) BARRIER;
  }

  // ---- epilogue: masked running max, butterfly over 32 col-lanes ----
  // C frag (32x32): col = l31, row = (j&3) + 8*(j>>2) + 4*h.
  bool colv[2];
  #pragma unroll
  for (int nf = 0; nf < 2; ++nf)
    colv[nf] = (lt * 128 + wc * 64 + nf * 32 + l31) < SCV;

  float rm[4][16];
  #pragma unroll
  for (int mf = 0; mf < 4; ++mf)
    #pragma unroll
    for (int j = 0; j < 16; ++j) {
      float v = -1e30f;
      #pragma unroll
      for (int nf = 0; nf < 2; ++nf)
        if (colv[nf]) v = fmaxf(v, acc[mf][nf][j]);
      rm[mf][j] = v;
    }

  #pragma unroll
  for (int msk = 1; msk < 32; msk <<= 1)
    #pragma unroll
    for (int mf = 0; mf < 4; ++mf)
      #pragma unroll
      for (int j = 0; j < 16; ++j)
        rm[mf][j] = fmaxf(rm[mf][j], __shfl_xor(rm[mf][j], msk));

  __syncthreads();
  float* buf = reinterpret_cast<float*>(&ring[0][0]);  // 2 x 256 floats
  if (l31 == 0) {
    #pragma unroll
    for (int mf = 0; mf < 4; ++mf)
      #pragma unroll
      for (int j = 0; j < 16; ++j) {
        int r = wr * 128 + mf * 32 + (j & 3) + 8 * (j >> 2) + 4 * h;  // 0..255
        buf[wc * 256 + r] = rm[mf][j];
      }
  }
  __syncthreads();
  if (tid < 256) {
    float v = fmaxf(buf[tid], buf[256 + tid]);
    part[((size_t)n * NST + st) * MQP + (size_t)mt * 256 + tid] = v;
  }
}

extern "C" __global__ void finalize_kernel(const float* __restrict__ part,
                                           float* __restrict__ out) {
  int i = blockIdx.x * 256 + threadIdx.x;
  if (i >= NB * SCV) return;
  int n = i / SCV, q = i - n * SCV;
  const float* p = part + (size_t)n * NST * MQP + q;
  float m = p[0];
  #pragma unroll 4
  for (int g = 1; g < NST; ++g) m = fmaxf(m, p[(size_t)g * MQP]);
  out[i] = 1.0f - m;
}

extern "C" void kernel_launch(void* const* d_in, const int* in_sizes, int n_in,
                              void* d_out, int out_size, void* d_ws, size_t ws_size,
                              hipStream_t stream) {
  const float* q_feats = (const float*)d_in[0];  // (3, 8, 1370, 768) f32
  const float* s_feats = (const float*)d_in[1];  // (3, 32, 1370, 768) f32
  float* out = (float*)d_out;                    // (8, 1, 37, 37) f32

  char* ws = (char*)d_ws;
  const size_t xq_bytes = (size_t)NB * MQP * DDIM;     // 9,437,184 (fp8)
  const size_t xs_bytes = (size_t)NSLAB * SCP * DDIM;  // 34,603,008 (fp8)
  unsigned char* xq = (unsigned char*)ws;
  unsigned char* xs = (unsigned char*)(ws + xq_bytes);
  float* part       = (float*)(ws + xq_bytes + xs_bytes); // 8*44*1536 floats

  prep_kernel<<<dim3(MQP, NB), 192, 0, stream>>>(
      q_feats, xq, (size_t)NB * T_TOK * DDIM);
  prep_kernel<<<dim3(SCP, NSLAB), 192, 0, stream>>>(
      s_feats, xs, (size_t)NSLAB * T_TOK * DDIM);
  simmax_kernel<<<dim3(NMT, NST, NB), 256, 0, stream>>>(xq, xs, part);
  finalize_kernel<<<dim3((NB * SCV + 255) / 256), 256, 0, stream>>>(part, out);
}